// Round 1
// baseline (1733.530 us; speedup 1.0000x reference)
//
#include <hip/hip_runtime.h>
#include <math.h>

#define NSEQ 2048
#define NFFT 4096
#define D1C  1536
#define EMBC 512
#define BATCH 4

__device__ __forceinline__ float silu_f(float y) { return y / (1.f + expf(-y)); }

// ---------------------------------------------------------------------------
// row-norm scale: scale[row] = 1/(||x_row|| * D1^-0.5 + 1e-8)
__global__ __launch_bounds__(256) void scale_kernel(const float* __restrict__ x,
                                                    float* __restrict__ scale) {
    int row  = blockIdx.x * 4 + (threadIdx.x >> 6);
    int lane = threadIdx.x & 63;
    const float* xr = x + (size_t)row * EMBC;
    float ss = 0.f;
#pragma unroll
    for (int k = 0; k < EMBC / 64; ++k) { float v = xr[lane + k * 64]; ss += v * v; }
#pragma unroll
    for (int off = 32; off >= 1; off >>= 1) ss += __shfl_xor(ss, off);
    if (lane == 0) scale[row] = 1.f / (sqrtf(ss) * 0.02551551815399144f + 1e-8f);
}

// ---------------------------------------------------------------------------
// RPE MLP: 4096 positions -> a_c[col][pos] (complex, imag=0), col = h*HD+d
__global__ __launch_bounds__(256) void rpe_kernel(
    const float* __restrict__ pw, const float* __restrict__ pb,
    const float* __restrict__ lw, const float* __restrict__ lb,
    const float* __restrict__ ow, const float* __restrict__ ob,
    float2* __restrict__ a_c) {
    __shared__ float hs[64][33];
    int tid = threadIdx.x;
    int s0  = blockIdx.x * 64;
    if (tid < 64) {
        int s = s0 + tid;
        float p = (s == 0 || s == 2048) ? 0.f : (s < 2048 ? (float)s : (float)(s - 4096));
        float h[32];
#pragma unroll
        for (int k = 0; k < 32; ++k) h[k] = fmaxf(p * pw[k] + pb[k], 0.f);
        for (int L = 0; L < 3; ++L) {
            float ss = 0.f;
#pragma unroll
            for (int k = 0; k < 32; ++k) ss += h[k] * h[k];
            float sc = 1.f / (sqrtf(ss) * 0.1767766952966369f + 1e-8f);
            float g[32];
#pragma unroll
            for (int k = 0; k < 32; ++k) g[k] = fmaxf(h[k] * sc, 0.f);
#pragma unroll
            for (int j = 0; j < 32; ++j) {
                float acc = lb[L * 32 + j];
#pragma unroll
                for (int k = 0; k < 32; ++k) acc += g[k] * lw[(L * 32 + k) * 32 + j];
                h[j] = acc;
            }
        }
        float ss = 0.f;
#pragma unroll
        for (int k = 0; k < 32; ++k) ss += h[k] * h[k];
        float sc = 1.f / (sqrtf(ss) * 0.1767766952966369f + 1e-8f);
#pragma unroll
        for (int k = 0; k < 32; ++k) hs[tid][k] = fmaxf(h[k] * sc, 0.f);
    }
    __syncthreads();
    // final 32 -> 1536 projection; each thread: 6 cols x 64 rows
    for (int cc = 0; cc < 6; ++cc) {
        int col = tid + cc * 256;
        float wcol[32];
#pragma unroll
        for (int k = 0; k < 32; ++k) wcol[k] = ow[k * D1C + col];
        float bb = ob[col];
        float2* outp = a_c + ((size_t)col << 12) + s0;
        for (int r = 0; r < 64; ++r) {
            float acc = bb;
#pragma unroll
            for (int k = 0; k < 32; ++k) acc += hs[r][k] * wcol[k];
            outp[r] = make_float2(acc, 0.f);
        }
    }
}

// ---------------------------------------------------------------------------
// in-LDS 4096-pt FFT: DIF fwd (natural->bitrev), DIT inv (bitrev->natural)
__device__ __forceinline__ void fft4096(float2* f, int tid, bool inverse) {
    if (!inverse) {
        for (int m = 2048; m >= 1; m >>= 1) {
            __syncthreads();
            float c0 = -(float)M_PI / (float)m;
            for (int p = tid; p < 2048; p += 256) {
                int j  = p & (m - 1);
                int i0 = ((p - j) << 1) + j;
                int i1 = i0 + m;
                float2 a = f[i0], b = f[i1];
                float dx = a.x - b.x, dy = a.y - b.y;
                f[i0] = make_float2(a.x + b.x, a.y + b.y);
                float sn, cs;
                __sincosf(c0 * (float)j, &sn, &cs);
                f[i1] = make_float2(dx * cs - dy * sn, dx * sn + dy * cs);
            }
        }
    } else {
        for (int m = 1; m <= 2048; m <<= 1) {
            __syncthreads();
            float c0 = (float)M_PI / (float)m;
            for (int p = tid; p < 2048; p += 256) {
                int j  = p & (m - 1);
                int i0 = ((p - j) << 1) + j;
                int i1 = i0 + m;
                float sn, cs;
                __sincosf(c0 * (float)j, &sn, &cs);
                float2 a = f[i0], b = f[i1];
                float wx = b.x * cs - b.y * sn, wy = b.x * sn + b.y * cs;
                f[i0] = make_float2(a.x + wx, a.y + wy);
                f[i1] = make_float2(a.x - wx, a.y - wy);
            }
        }
    }
    __syncthreads();
}

// forward-FFT the RPE coefficient rows in place (spectrum stays bit-reversed)
__global__ __launch_bounds__(256) void fft_a_kernel(float2* __restrict__ a_c) {
    __shared__ float2 cf[NFFT];
    int tid = threadIdx.x;
    float2* row = a_c + ((size_t)blockIdx.x << 12);
    for (int k = tid; k < NFFT; k += 256) cf[k] = row[k];
    fft4096(cf, tid, false);
    for (int k = tid; k < NFFT; k += 256) row[k] = cf[k];
}

// circular convolution per (b,h,d): v -> FFT -> *af -> IFFT -> t (in place)
__global__ __launch_bounds__(256) void conv_kernel(float* __restrict__ vt,
                                                   const float2* __restrict__ af) {
    __shared__ float2 cf[NFFT];
    int tid = threadIdx.x;
    int b   = blockIdx.x / D1C;
    int col = blockIdx.x % D1C;
    float* vrow        = vt + ((size_t)(b * D1C + col) << 11);
    const float2* arow = af + ((size_t)col << 12);
    for (int k = tid; k < 2048; k += 256) {
        cf[k]        = make_float2(vrow[k], 0.f);
        cf[k + 2048] = make_float2(0.f, 0.f);
    }
    fft4096(cf, tid, false);
    const float inv = 1.0f / 4096.0f;
    for (int k = tid; k < NFFT; k += 256) {
        float2 z = cf[k], w = arow[k];
        cf[k] = make_float2((z.x * w.x - z.y * w.y) * inv,
                            (z.x * w.y + z.y * w.x) * inv);
    }
    fft4096(cf, tid, true);
    for (int k = tid; k < 2048; k += 256) vrow[k] = cf[k].x;
}

// ---------------------------------------------------------------------------
// fp32 tiled GEMM, 128x128x16, 256 threads, 8x8 per thread, fused A/epilogue
enum { AM_SCALED, AM_MULT, AM_ADD, AM_PLAIN };
enum { EP_SILU, EP_SILU_VT, EP_PLAIN, EP_MUL };

template <int K, int AMODE, int EPI>
__global__ __launch_bounds__(256) void gemm_k(
    const float* __restrict__ A0, const float* __restrict__ A1,
    const float* __restrict__ W, const float* __restrict__ bias,
    const float* __restrict__ E0, float* __restrict__ Out, int Nc) {
    __shared__ float As[16][128];
    __shared__ float Bs[16][128];
    int tid  = threadIdx.x;
    int row0 = blockIdx.x * 128, col0 = blockIdx.y * 128;
    int tx = tid & 15, ty = tid >> 4;
    float acc[8][8];
#pragma unroll
    for (int i = 0; i < 8; ++i)
#pragma unroll
        for (int j = 0; j < 8; ++j) acc[i][j] = 0.f;

    for (int k0 = 0; k0 < K; k0 += 16) {
#pragma unroll
        for (int l = 0; l < 8; ++l) {
            int e  = tid + l * 256;
            int r  = e >> 4, kk = e & 15;
            int row = row0 + r, kg = k0 + kk;
            float v;
            if constexpr (AMODE == AM_SCALED)
                v = A0[(size_t)row * K + kg] * A1[row];
            else if constexpr (AMODE == AM_ADD)
                v = A0[(size_t)row * K + kg] + A1[(size_t)row * K + kg];
            else if constexpr (AMODE == AM_MULT) {
                int b = row >> 11, ii = row & 2047;
                v = A0[(size_t)row * K + kg] * A1[((size_t)(b * D1C + kg) << 11) + ii];
            } else
                v = A0[(size_t)row * K + kg];
            As[kk][r] = v;
        }
#pragma unroll
        for (int l = 0; l < 8; ++l) {
            int e  = tid + l * 256;
            int kk = e >> 7, c = e & 127;
            Bs[kk][c] = W[(size_t)(k0 + kk) * Nc + col0 + c];
        }
        __syncthreads();
#pragma unroll
        for (int kk = 0; kk < 16; ++kk) {
            float a[8], b[8];
#pragma unroll
            for (int i = 0; i < 8; ++i) a[i] = As[kk][ty * 8 + i];
#pragma unroll
            for (int j = 0; j < 8; ++j) b[j] = Bs[kk][tx * 8 + j];
#pragma unroll
            for (int i = 0; i < 8; ++i)
#pragma unroll
                for (int j = 0; j < 8; ++j) acc[i][j] = fmaf(a[i], b[j], acc[i][j]);
        }
        __syncthreads();
    }

#pragma unroll
    for (int i = 0; i < 8; ++i) {
        int row = row0 + ty * 8 + i;
#pragma unroll
        for (int j = 0; j < 8; ++j) {
            int col = col0 + tx * 8 + j;
            float y = acc[i][j] + bias[col];
            if constexpr (EPI == EP_SILU)
                Out[(size_t)row * Nc + col] = silu_f(y);
            else if constexpr (EPI == EP_SILU_VT) {
                int b = row >> 11, ii = row & 2047;
                Out[((size_t)(b * D1C + col) << 11) + ii] = silu_f(y);
            } else if constexpr (EPI == EP_PLAIN)
                Out[(size_t)row * Nc + col] = y;
            else
                Out[(size_t)row * Nc + col] = y * E0[(size_t)row * Nc + col];
        }
    }
}

// ---------------------------------------------------------------------------
extern "C" void kernel_launch(void* const* d_in, const int* in_sizes, int n_in,
                              void* d_out, int out_size, void* d_ws, size_t ws_size,
                              hipStream_t stream) {
    const float* x   = (const float*)d_in[1];
    const float* u_w = (const float*)d_in[2];
    const float* u_b = (const float*)d_in[3];
    const float* v_w = (const float*)d_in[4];
    const float* v_b = (const float*)d_in[5];
    const float* o_w = (const float*)d_in[6];
    const float* o_b = (const float*)d_in[7];
    const float* rpw = (const float*)d_in[8];
    const float* rpb = (const float*)d_in[9];
    const float* rlw = (const float*)d_in[10];
    const float* rlb = (const float*)d_in[11];
    const float* row_w = (const float*)d_in[12];
    const float* rob = (const float*)d_in[13];
    const float* g1w = (const float*)d_in[14];
    const float* g1b = (const float*)d_in[15];
    const float* g2w = (const float*)d_in[16];
    const float* g2b = (const float*)d_in[17];
    const float* g3w = (const float*)d_in[18];
    const float* g3b = (const float*)d_in[19];

    float* ws = (float*)d_ws;
    // layout (floats): scale 8192 | a_c 12,582,912 | vt 12,582,912 | u 12,582,912
    float*  scale = ws;
    float2* a_c   = (float2*)(ws + 8192);
    float*  vt    = ws + 8192 + 12582912;
    float*  u     = vt + 12582912;
    float*  tmp1  = (float*)a_c;  // reuse after conv consumed a_c
    float*  sbuf  = vt;           // reuse after out-GEMM consumed vt

    float* g_out   = (float*)d_out;
    float* out_out = g_out + (size_t)BATCH * NSEQ * EMBC;

    scale_kernel<<<2048, 256, 0, stream>>>(x, scale);
    rpe_kernel<<<64, 256, 0, stream>>>(rpw, rpb, rlw, rlb, row_w, rob, a_c);
    fft_a_kernel<<<1536, 256, 0, stream>>>(a_c);
    gemm_k<512, AM_SCALED, EP_SILU><<<dim3(64, 12), 256, 0, stream>>>(
        x, scale, u_w, u_b, nullptr, u, 1536);
    gemm_k<512, AM_SCALED, EP_SILU_VT><<<dim3(64, 12), 256, 0, stream>>>(
        x, scale, v_w, v_b, nullptr, vt, 1536);
    conv_kernel<<<6144, 256, 0, stream>>>(vt, a_c);
    gemm_k<1536, AM_MULT, EP_PLAIN><<<dim3(64, 4), 256, 0, stream>>>(
        u, vt, o_w, o_b, nullptr, out_out, 512);
    gemm_k<512, AM_ADD, EP_SILU><<<dim3(64, 12), 256, 0, stream>>>(
        out_out, x, g1w, g1b, nullptr, tmp1, 1536);
    gemm_k<512, AM_ADD, EP_MUL><<<dim3(64, 12), 256, 0, stream>>>(
        out_out, x, g2w, g2b, tmp1, sbuf, 1536);
    gemm_k<1536, AM_PLAIN, EP_PLAIN><<<dim3(64, 4), 256, 0, stream>>>(
        sbuf, nullptr, g3w, g3b, nullptr, g_out, 512);
}

// Round 2
// 928.696 us; speedup vs baseline: 1.8666x; 1.8666x over previous
//
#include <hip/hip_runtime.h>
#include <math.h>

#define NSEQ 2048
#define NFFT 4096
#define D1C  1536
#define EMBC 512
#define BATCH 4

typedef __fp16 f16;
typedef __fp16 f16x8 __attribute__((ext_vector_type(8)));
typedef __fp16 f16x4 __attribute__((ext_vector_type(4)));
typedef float  f32x4 __attribute__((ext_vector_type(4)));
typedef unsigned int u32;

__device__ __forceinline__ float silu_f(float y) { return y / (1.f + expf(-y)); }

// ---------------------------------------------------------------------------
// row-norm scale: scale[row] = 1/(||x_row|| * D1^-0.5 + 1e-8)
__global__ __launch_bounds__(256) void scale_kernel(const float* __restrict__ x,
                                                    float* __restrict__ scale) {
    int row  = blockIdx.x * 4 + (threadIdx.x >> 6);
    int lane = threadIdx.x & 63;
    const float* xr = x + (size_t)row * EMBC;
    float ss = 0.f;
#pragma unroll
    for (int k = 0; k < EMBC / 64; ++k) { float v = xr[lane + k * 64]; ss += v * v; }
#pragma unroll
    for (int off = 32; off >= 1; off >>= 1) ss += __shfl_xor(ss, off);
    if (lane == 0) scale[row] = 1.f / (sqrtf(ss) * 0.02551551815399144f + 1e-8f);
}

// xn = x * scale  -> f16 hi/lo
__global__ __launch_bounds__(256) void convert_xn_kernel(
    const float* __restrict__ x, const float* __restrict__ scale,
    f16* __restrict__ xh, f16* __restrict__ xl) {
    size_t i = ((size_t)blockIdx.x * 256 + threadIdx.x) * 4;
    float4 v = *reinterpret_cast<const float4*>(x + i);
    float s = scale[i >> 9];
    f16x4 h, l;
    const float* vv = (const float*)&v;
#pragma unroll
    for (int j = 0; j < 4; ++j) {
        float val = vv[j] * s;
        f16 hh = (f16)val;
        h[j] = hh; l[j] = (f16)(val - (float)hh);
    }
    *reinterpret_cast<f16x4*>(xh + i) = h;
    *reinterpret_cast<f16x4*>(xl + i) = l;
}

// x2 = a + b -> f16 hi/lo
__global__ __launch_bounds__(256) void convert_x2_kernel(
    const float* __restrict__ a, const float* __restrict__ b,
    f16* __restrict__ xh, f16* __restrict__ xl) {
    size_t i = ((size_t)blockIdx.x * 256 + threadIdx.x) * 4;
    float4 va = *reinterpret_cast<const float4*>(a + i);
    float4 vb = *reinterpret_cast<const float4*>(b + i);
    const float* pa = (const float*)&va;
    const float* pb = (const float*)&vb;
    f16x4 h, l;
#pragma unroll
    for (int j = 0; j < 4; ++j) {
        float val = pa[j] + pb[j];
        f16 hh = (f16)val;
        h[j] = hh; l[j] = (f16)(val - (float)hh);
    }
    *reinterpret_cast<f16x4*>(xh + i) = h;
    *reinterpret_cast<f16x4*>(xl + i) = l;
}

// W[K][N] fp32 -> WT[N][K] f16 hi/lo (LDS tile transpose)
__global__ __launch_bounds__(256) void wtrans_kernel(const float* __restrict__ W,
        f16* __restrict__ Th, f16* __restrict__ Tl, int Kd, int Nd) {
    __shared__ float t[32][33];
    int tx = threadIdx.x & 31, ty = threadIdx.x >> 5;
    int n0 = blockIdx.x * 32, k0 = blockIdx.y * 32;
#pragma unroll
    for (int yy = ty; yy < 32; yy += 8)
        t[yy][tx] = W[(size_t)(k0 + yy) * Nd + n0 + tx];
    __syncthreads();
#pragma unroll
    for (int yy = ty; yy < 32; yy += 8) {
        float v = t[tx][yy];
        f16 h = (f16)v;
        size_t o = (size_t)(n0 + yy) * Kd + k0 + tx;
        Th[o] = h; Tl[o] = (f16)(v - (float)h);
    }
}

// p = u * t (vt layout [b][col][n]) -> f16 hi/lo row-major [8192][1536]
__global__ __launch_bounds__(256) void convert_p_kernel(
    const float* __restrict__ u, const float* __restrict__ vt,
    f16* __restrict__ ph, f16* __restrict__ pl) {
    __shared__ float t[32][33];
    int b = blockIdx.z, n0 = blockIdx.x * 32, c0 = blockIdx.y * 32;
    int tx = threadIdx.x & 31, ty = threadIdx.x >> 5;
#pragma unroll
    for (int yy = ty; yy < 32; yy += 8)
        t[yy][tx] = vt[(((size_t)(b * D1C + c0 + yy)) << 11) + n0 + tx];
    __syncthreads();
#pragma unroll
    for (int yy = ty; yy < 32; yy += 8) {
        int row = b * NSEQ + n0 + yy;
        size_t idx = (size_t)row * D1C + c0 + tx;
        float val = u[idx] * t[tx][yy];
        f16 h = (f16)val;
        ph[idx] = h; pl[idx] = (f16)(val - (float)h);
    }
}

// ---------------------------------------------------------------------------
// RPE MLP: 4096 positions -> a_c[col][pos] (complex, imag=0), col = h*HD+d
__global__ __launch_bounds__(256) void rpe_kernel(
    const float* __restrict__ pw, const float* __restrict__ pb,
    const float* __restrict__ lw, const float* __restrict__ lb,
    const float* __restrict__ ow, const float* __restrict__ ob,
    float2* __restrict__ a_c) {
    __shared__ float hs[64][33];
    int tid = threadIdx.x;
    int s0  = blockIdx.x * 64;
    if (tid < 64) {
        int s = s0 + tid;
        float p = (s == 0 || s == 2048) ? 0.f : (s < 2048 ? (float)s : (float)(s - 4096));
        float h[32];
#pragma unroll
        for (int k = 0; k < 32; ++k) h[k] = fmaxf(p * pw[k] + pb[k], 0.f);
        for (int L = 0; L < 3; ++L) {
            float ss = 0.f;
#pragma unroll
            for (int k = 0; k < 32; ++k) ss += h[k] * h[k];
            float sc = 1.f / (sqrtf(ss) * 0.1767766952966369f + 1e-8f);
            float g[32];
#pragma unroll
            for (int k = 0; k < 32; ++k) g[k] = fmaxf(h[k] * sc, 0.f);
#pragma unroll
            for (int j = 0; j < 32; ++j) {
                float acc = lb[L * 32 + j];
#pragma unroll
                for (int k = 0; k < 32; ++k) acc += g[k] * lw[(L * 32 + k) * 32 + j];
                h[j] = acc;
            }
        }
        float ss = 0.f;
#pragma unroll
        for (int k = 0; k < 32; ++k) ss += h[k] * h[k];
        float sc = 1.f / (sqrtf(ss) * 0.1767766952966369f + 1e-8f);
#pragma unroll
        for (int k = 0; k < 32; ++k) hs[tid][k] = fmaxf(h[k] * sc, 0.f);
    }
    __syncthreads();
    for (int cc = 0; cc < 6; ++cc) {
        int col = tid + cc * 256;
        float wcol[32];
#pragma unroll
        for (int k = 0; k < 32; ++k) wcol[k] = ow[k * D1C + col];
        float bb = ob[col];
        float2* outp = a_c + ((size_t)col << 12) + s0;
        for (int r = 0; r < 64; ++r) {
            float acc = bb;
#pragma unroll
            for (int k = 0; k < 32; ++k) acc += hs[r][k] * wcol[k];
            outp[r] = make_float2(acc, 0.f);
        }
    }
}

// ---------------------------------------------------------------------------
// in-LDS 4096-pt FFT: DIF fwd (natural->bitrev), DIT inv (bitrev->natural)
__device__ __forceinline__ void fft4096(float2* f, int tid, bool inverse) {
    if (!inverse) {
        for (int m = 2048; m >= 1; m >>= 1) {
            __syncthreads();
            float c0 = -(float)M_PI / (float)m;
            for (int p = tid; p < 2048; p += 256) {
                int j  = p & (m - 1);
                int i0 = ((p - j) << 1) + j;
                int i1 = i0 + m;
                float2 a = f[i0], b = f[i1];
                float dx = a.x - b.x, dy = a.y - b.y;
                f[i0] = make_float2(a.x + b.x, a.y + b.y);
                float sn, cs;
                __sincosf(c0 * (float)j, &sn, &cs);
                f[i1] = make_float2(dx * cs - dy * sn, dx * sn + dy * cs);
            }
        }
    } else {
        for (int m = 1; m <= 2048; m <<= 1) {
            __syncthreads();
            float c0 = (float)M_PI / (float)m;
            for (int p = tid; p < 2048; p += 256) {
                int j  = p & (m - 1);
                int i0 = ((p - j) << 1) + j;
                int i1 = i0 + m;
                float sn, cs;
                __sincosf(c0 * (float)j, &sn, &cs);
                float2 a = f[i0], b = f[i1];
                float wx = b.x * cs - b.y * sn, wy = b.x * sn + b.y * cs;
                f[i0] = make_float2(a.x + wx, a.y + wy);
                f[i1] = make_float2(a.x - wx, a.y - wy);
            }
        }
    }
    __syncthreads();
}

__global__ __launch_bounds__(256) void fft_a_kernel(float2* __restrict__ a_c) {
    __shared__ float2 cf[NFFT];
    int tid = threadIdx.x;
    float2* row = a_c + ((size_t)blockIdx.x << 12);
    for (int k = tid; k < NFFT; k += 256) cf[k] = row[k];
    fft4096(cf, tid, false);
    for (int k = tid; k < NFFT; k += 256) row[k] = cf[k];
}

__global__ __launch_bounds__(256) void conv_kernel(float* __restrict__ vt,
                                                   const float2* __restrict__ af) {
    __shared__ float2 cf[NFFT];
    int tid = threadIdx.x;
    int b   = blockIdx.x / D1C;
    int col = blockIdx.x % D1C;
    float* vrow        = vt + ((size_t)(b * D1C + col) << 11);
    const float2* arow = af + ((size_t)col << 12);
    for (int k = tid; k < 2048; k += 256) {
        cf[k]        = make_float2(vrow[k], 0.f);
        cf[k + 2048] = make_float2(0.f, 0.f);
    }
    fft4096(cf, tid, false);
    const float inv = 1.0f / 4096.0f;
    for (int k = tid; k < NFFT; k += 256) {
        float2 z = cf[k], w = arow[k];
        cf[k] = make_float2((z.x * w.x - z.y * w.y) * inv,
                            (z.x * w.y + z.y * w.x) * inv);
    }
    fft4096(cf, tid, true);
    for (int k = tid; k < 2048; k += 256) vrow[k] = cf[k].x;
}

// ---------------------------------------------------------------------------
// MFMA split-fp16 GEMM: C = (Ah+Al)(Bh+Bl) - AlBl, fp32 accum.
// A row-major [M][K] (hi/lo), B given transposed [N][K] (hi/lo).
// 128x128 tile, BK=32, 4 waves (each 64x64), double-buffered global_load_lds.
enum { EP_SILU_F32, EP_SILU_VT, EP_PLAIN, EP_GLU2 };

template <int K, int EPI>
__global__ __launch_bounds__(256, 2) void mgemm(
    const f16* __restrict__ Ah, const f16* __restrict__ Al,
    const f16* __restrict__ Bh, const f16* __restrict__ Bl,
    const float* __restrict__ bias, const float* __restrict__ E0,
    float* __restrict__ OutF, f16* __restrict__ OutH, f16* __restrict__ OutL,
    int Ncols) {
    __shared__ __align__(16) char smem[65536];
    const int tid  = threadIdx.x;
    const int w    = tid >> 6, lane = tid & 63;
    const int wr   = w >> 1, wc = w & 1;
    const int l15  = lane & 15, kc = lane >> 4;
    const int row0 = blockIdx.x * 128, col0 = blockIdx.y * 128;

    f32x4 acc[4][4] = {};

    auto stage = [&](int buf, int kt) {
        const int k0 = kt * 32;
#pragma unroll
        for (int c = 0; c < 2; ++c) {
            int p = tid + c * 256;                 // 16B-position: kc*128 + row
            int r = p & 127, kk = p >> 7;
            const f16* ga = Ah + (size_t)(row0 + r) * K + k0 + kk * 8;
            const f16* gb = Al + (size_t)(row0 + r) * K + k0 + kk * 8;
            const f16* gc = Bh + (size_t)(col0 + r) * K + k0 + kk * 8;
            const f16* gd = Bl + (size_t)(col0 + r) * K + k0 + kk * 8;
            u32 off = (u32)buf * 32768u + (u32)(c * 256 + w * 64) * 16u;  // wave-uniform
            __builtin_amdgcn_global_load_lds((const __attribute__((address_space(1))) u32*)ga,
                (__attribute__((address_space(3))) u32*)(smem + off), 16, 0, 0);
            __builtin_amdgcn_global_load_lds((const __attribute__((address_space(1))) u32*)gb,
                (__attribute__((address_space(3))) u32*)(smem + off + 8192), 16, 0, 0);
            __builtin_amdgcn_global_load_lds((const __attribute__((address_space(1))) u32*)gc,
                (__attribute__((address_space(3))) u32*)(smem + off + 16384), 16, 0, 0);
            __builtin_amdgcn_global_load_lds((const __attribute__((address_space(1))) u32*)gd,
                (__attribute__((address_space(3))) u32*)(smem + off + 24576), 16, 0, 0);
        }
    };

    auto compute = [&](int buf) {
        const char* base = smem + buf * 32768;
        f16x8 a_h[4], a_l[4], b_h[4], b_l[4];
#pragma unroll
        for (int m = 0; m < 4; ++m) {
            int r = wr * 64 + m * 16 + l15;
            a_h[m] = *(const f16x8*)(base + (kc * 128 + r) * 16);
            a_l[m] = *(const f16x8*)(base + 8192 + (kc * 128 + r) * 16);
        }
#pragma unroll
        for (int n = 0; n < 4; ++n) {
            int r = wc * 64 + n * 16 + l15;
            b_h[n] = *(const f16x8*)(base + 16384 + (kc * 128 + r) * 16);
            b_l[n] = *(const f16x8*)(base + 24576 + (kc * 128 + r) * 16);
        }
#pragma unroll
        for (int m = 0; m < 4; ++m)
#pragma unroll
            for (int n = 0; n < 4; ++n) {
                acc[m][n] = __builtin_amdgcn_mfma_f32_16x16x32_f16(a_h[m], b_h[n], acc[m][n], 0, 0, 0);
                acc[m][n] = __builtin_amdgcn_mfma_f32_16x16x32_f16(a_h[m], b_l[n], acc[m][n], 0, 0, 0);
                acc[m][n] = __builtin_amdgcn_mfma_f32_16x16x32_f16(a_l[m], b_h[n], acc[m][n], 0, 0, 0);
            }
    };

    constexpr int NT = K / 32;
    stage(0, 0);
    __syncthreads();
    int cur = 0;
    for (int t = 0; t < NT; ++t) {
        if (t + 1 < NT) stage(cur ^ 1, t + 1);
        compute(cur);
        __syncthreads();
        cur ^= 1;
    }

#pragma unroll
    for (int m = 0; m < 4; ++m) {
        int rbase = row0 + wr * 64 + m * 16 + kc * 4;
#pragma unroll
        for (int n = 0; n < 4; ++n) {
            int col = col0 + wc * 64 + n * 16 + l15;
            float bb = bias[col];
#pragma unroll
            for (int r = 0; r < 4; ++r) {
                int row = rbase + r;
                float y = acc[m][n][r] + bb;
                size_t idx = (size_t)row * Ncols + col;
                if constexpr (EPI == EP_SILU_F32) {
                    OutF[idx] = silu_f(y);
                } else if constexpr (EPI == EP_SILU_VT) {
                    int bI = row >> 11, ni = row & 2047;
                    OutF[(((size_t)(bI * D1C + col)) << 11) + ni] = silu_f(y);
                } else if constexpr (EPI == EP_PLAIN) {
                    OutF[idx] = y;
                } else {  // EP_GLU2: z = E0 * y -> f16 hi/lo
                    float z = E0[idx] * y;
                    f16 h = (f16)z;
                    OutH[idx] = h;
                    OutL[idx] = (f16)(z - (float)h);
                }
            }
        }
    }
}

// ---------------------------------------------------------------------------
extern "C" void kernel_launch(void* const* d_in, const int* in_sizes, int n_in,
                              void* d_out, int out_size, void* d_ws, size_t ws_size,
                              hipStream_t stream) {
    const float* x   = (const float*)d_in[1];
    const float* u_w = (const float*)d_in[2];
    const float* u_b = (const float*)d_in[3];
    const float* v_w = (const float*)d_in[4];
    const float* v_b = (const float*)d_in[5];
    const float* o_w = (const float*)d_in[6];
    const float* o_b = (const float*)d_in[7];
    const float* rpw = (const float*)d_in[8];
    const float* rpb = (const float*)d_in[9];
    const float* rlw = (const float*)d_in[10];
    const float* rlb = (const float*)d_in[11];
    const float* row_w = (const float*)d_in[12];
    const float* rob = (const float*)d_in[13];
    const float* g1w = (const float*)d_in[14];
    const float* g1b = (const float*)d_in[15];
    const float* g2w = (const float*)d_in[16];
    const float* g2b = (const float*)d_in[17];
    const float* g3w = (const float*)d_in[18];
    const float* g3b = (const float*)d_in[19];

    // workspace layout (bytes)
    char* wsb = (char*)d_ws;
    float* scale = (float*)wsb;                       // 32 KB (64 KB slot)
    char* R1 = wsb + (1 << 16);                       // 50331648: a_c, later ph+pl
    char* R2 = R1 + 50331648;                         // 50331648: vt, later tmp1
    char* R3 = R2 + 50331648;                         // 50331648: u, later zh+zl
    char* R4 = R3 + 50331648;                         // 16777216: xn hi/lo, later x2 hi/lo
    char* R5 = R4 + 16777216;                         // 18874368: 6 transposed split weights

    float2* a_c  = (float2*)R1;
    f16*    ph   = (f16*)R1;
    f16*    pl   = (f16*)(R1 + 25165824);
    float*  vt   = (float*)R2;
    float*  tmp1 = (float*)R2;
    float*  u    = (float*)R3;
    f16*    zh   = (f16*)R3;
    f16*    zl   = (f16*)(R3 + 25165824);
    f16*    xnh  = (f16*)R4;
    f16*    xnl  = (f16*)(R4 + 8388608);
    f16*    x2h  = xnh;  // reuse after xn dead
    f16*    x2l  = xnl;

    auto wTh = [&](int i) { return (f16*)(R5 + (size_t)i * 3145728); };
    auto wTl = [&](int i) { return (f16*)(R5 + (size_t)i * 3145728 + 1572864); };

    float* g_out   = (float*)d_out;
    float* out_out = g_out + (size_t)BATCH * NSEQ * EMBC;

    // prologue: norms, splits, weight transposes, RPE spectrum
    scale_kernel<<<2048, 256, 0, stream>>>(x, scale);
    convert_xn_kernel<<<4096, 256, 0, stream>>>(x, scale, xnh, xnl);
    wtrans_kernel<<<dim3(48, 16), 256, 0, stream>>>(u_w, wTh(0), wTl(0), 512, 1536);
    wtrans_kernel<<<dim3(48, 16), 256, 0, stream>>>(v_w, wTh(1), wTl(1), 512, 1536);
    wtrans_kernel<<<dim3(16, 48), 256, 0, stream>>>(o_w, wTh(2), wTl(2), 1536, 512);
    wtrans_kernel<<<dim3(48, 16), 256, 0, stream>>>(g1w, wTh(3), wTl(3), 512, 1536);
    wtrans_kernel<<<dim3(48, 16), 256, 0, stream>>>(g2w, wTh(4), wTl(4), 512, 1536);
    wtrans_kernel<<<dim3(16, 48), 256, 0, stream>>>(g3w, wTh(5), wTl(5), 1536, 512);
    rpe_kernel<<<64, 256, 0, stream>>>(rpw, rpb, rlw, rlb, row_w, rob, a_c);
    fft_a_kernel<<<1536, 256, 0, stream>>>(a_c);

    // u, v projections
    mgemm<512, EP_SILU_F32><<<dim3(64, 12), 256, 0, stream>>>(
        xnh, xnl, wTh(0), wTl(0), u_b, nullptr, u, nullptr, nullptr, 1536);
    mgemm<512, EP_SILU_VT><<<dim3(64, 12), 256, 0, stream>>>(
        xnh, xnl, wTh(1), wTl(1), v_b, nullptr, vt, nullptr, nullptr, 1536);

    // Toeplitz via FFT conv (in place on vt), then p = u * t -> f16 split
    conv_kernel<<<6144, 256, 0, stream>>>(vt, a_c);
    convert_p_kernel<<<dim3(64, 48, 4), 256, 0, stream>>>(u, vt, ph, pl);

    // out = p @ o_w + o_b
    mgemm<1536, EP_PLAIN><<<dim3(64, 4), 256, 0, stream>>>(
        ph, pl, wTh(2), wTl(2), o_b, nullptr, out_out, nullptr, nullptr, 512);

    // GLU
    convert_x2_kernel<<<4096, 256, 0, stream>>>(out_out, x, x2h, x2l);
    mgemm<512, EP_SILU_F32><<<dim3(64, 12), 256, 0, stream>>>(
        x2h, x2l, wTh(3), wTl(3), g1b, nullptr, tmp1, nullptr, nullptr, 1536);
    mgemm<512, EP_GLU2><<<dim3(64, 12), 256, 0, stream>>>(
        x2h, x2l, wTh(4), wTl(4), g2b, tmp1, nullptr, zh, zl, 1536);
    mgemm<1536, EP_PLAIN><<<dim3(64, 4), 256, 0, stream>>>(
        zh, zl, wTh(5), wTl(5), g3b, nullptr, g_out, nullptr, nullptr, 512);
}

// Round 3
// 793.353 us; speedup vs baseline: 2.1851x; 1.1706x over previous
//
#include <hip/hip_runtime.h>
#include <math.h>

#define NSEQ 2048
#define NFFT 4096
#define D1C  1536
#define EMBC 512
#define BATCH 4

typedef __fp16 f16;
typedef __fp16 f16x8 __attribute__((ext_vector_type(8)));
typedef __fp16 f16x4 __attribute__((ext_vector_type(4)));
typedef float  f32x4 __attribute__((ext_vector_type(4)));
typedef unsigned int u32;

__device__ __forceinline__ float silu_f(float y) { return y / (1.f + expf(-y)); }

// ---------------------------------------------------------------------------
// row-norm scale: scale[row] = 1/(||x_row|| * D1^-0.5 + 1e-8)
__global__ __launch_bounds__(256) void scale_kernel(const float* __restrict__ x,
                                                    float* __restrict__ scale) {
    int row  = blockIdx.x * 4 + (threadIdx.x >> 6);
    int lane = threadIdx.x & 63;
    const float* xr = x + (size_t)row * EMBC;
    float ss = 0.f;
#pragma unroll
    for (int k = 0; k < EMBC / 64; ++k) { float v = xr[lane + k * 64]; ss += v * v; }
#pragma unroll
    for (int off = 32; off >= 1; off >>= 1) ss += __shfl_xor(ss, off);
    if (lane == 0) scale[row] = 1.f / (sqrtf(ss) * 0.02551551815399144f + 1e-8f);
}

// xn = x * scale  -> f16 hi/lo
__global__ __launch_bounds__(256) void convert_xn_kernel(
    const float* __restrict__ x, const float* __restrict__ scale,
    f16* __restrict__ xh, f16* __restrict__ xl) {
    size_t i = ((size_t)blockIdx.x * 256 + threadIdx.x) * 4;
    float4 v = *reinterpret_cast<const float4*>(x + i);
    float s = scale[i >> 9];
    f16x4 h, l;
    const float* vv = (const float*)&v;
#pragma unroll
    for (int j = 0; j < 4; ++j) {
        float val = vv[j] * s;
        f16 hh = (f16)val;
        h[j] = hh; l[j] = (f16)(val - (float)hh);
    }
    *reinterpret_cast<f16x4*>(xh + i) = h;
    *reinterpret_cast<f16x4*>(xl + i) = l;
}

// x2 = a + b -> f16 hi/lo
__global__ __launch_bounds__(256) void convert_x2_kernel(
    const float* __restrict__ a, const float* __restrict__ b,
    f16* __restrict__ xh, f16* __restrict__ xl) {
    size_t i = ((size_t)blockIdx.x * 256 + threadIdx.x) * 4;
    float4 va = *reinterpret_cast<const float4*>(a + i);
    float4 vb = *reinterpret_cast<const float4*>(b + i);
    const float* pa = (const float*)&va;
    const float* pb = (const float*)&vb;
    f16x4 h, l;
#pragma unroll
    for (int j = 0; j < 4; ++j) {
        float val = pa[j] + pb[j];
        f16 hh = (f16)val;
        h[j] = hh; l[j] = (f16)(val - (float)hh);
    }
    *reinterpret_cast<f16x4*>(xh + i) = h;
    *reinterpret_cast<f16x4*>(xl + i) = l;
}

// W[K][N] fp32 -> WT[N][K] f16 hi/lo (LDS tile transpose)
__global__ __launch_bounds__(256) void wtrans_kernel(const float* __restrict__ W,
        f16* __restrict__ Th, f16* __restrict__ Tl, int Kd, int Nd) {
    __shared__ float t[32][33];
    int tx = threadIdx.x & 31, ty = threadIdx.x >> 5;
    int n0 = blockIdx.x * 32, k0 = blockIdx.y * 32;
#pragma unroll
    for (int yy = ty; yy < 32; yy += 8)
        t[yy][tx] = W[(size_t)(k0 + yy) * Nd + n0 + tx];
    __syncthreads();
#pragma unroll
    for (int yy = ty; yy < 32; yy += 8) {
        float v = t[tx][yy];
        f16 h = (f16)v;
        size_t o = (size_t)(n0 + yy) * Kd + k0 + tx;
        Th[o] = h; Tl[o] = (f16)(v - (float)h);
    }
}

// p = u * t (vt layout [b][col][n]) -> f16 hi/lo row-major [8192][1536]
__global__ __launch_bounds__(256) void convert_p_kernel(
    const float* __restrict__ u, const float* __restrict__ vt,
    f16* __restrict__ ph, f16* __restrict__ pl) {
    __shared__ float t[32][33];
    int b = blockIdx.z, n0 = blockIdx.x * 32, c0 = blockIdx.y * 32;
    int tx = threadIdx.x & 31, ty = threadIdx.x >> 5;
#pragma unroll
    for (int yy = ty; yy < 32; yy += 8)
        t[yy][tx] = vt[(((size_t)(b * D1C + c0 + yy)) << 11) + n0 + tx];
    __syncthreads();
#pragma unroll
    for (int yy = ty; yy < 32; yy += 8) {
        int row = b * NSEQ + n0 + yy;
        size_t idx = (size_t)row * D1C + c0 + tx;
        float val = u[idx] * t[tx][yy];
        f16 h = (f16)val;
        ph[idx] = h; pl[idx] = (f16)(val - (float)h);
    }
}

// ---------------------------------------------------------------------------
// RPE MLP: 4096 positions -> a_r[col][pos] (real), col = h*HD+d
__global__ __launch_bounds__(256) void rpe_kernel(
    const float* __restrict__ pw, const float* __restrict__ pb,
    const float* __restrict__ lw, const float* __restrict__ lb,
    const float* __restrict__ ow, const float* __restrict__ ob,
    float* __restrict__ a_r) {
    __shared__ float hs[64][33];
    int tid = threadIdx.x;
    int s0  = blockIdx.x * 64;
    if (tid < 64) {
        int s = s0 + tid;
        float p = (s == 0 || s == 2048) ? 0.f : (s < 2048 ? (float)s : (float)(s - 4096));
        float h[32];
#pragma unroll
        for (int k = 0; k < 32; ++k) h[k] = fmaxf(p * pw[k] + pb[k], 0.f);
        for (int L = 0; L < 3; ++L) {
            float ss = 0.f;
#pragma unroll
            for (int k = 0; k < 32; ++k) ss += h[k] * h[k];
            float sc = 1.f / (sqrtf(ss) * 0.1767766952966369f + 1e-8f);
            float g[32];
#pragma unroll
            for (int k = 0; k < 32; ++k) g[k] = fmaxf(h[k] * sc, 0.f);
#pragma unroll
            for (int j = 0; j < 32; ++j) {
                float acc = lb[L * 32 + j];
#pragma unroll
                for (int k = 0; k < 32; ++k) acc += g[k] * lw[(L * 32 + k) * 32 + j];
                h[j] = acc;
            }
        }
        float ss = 0.f;
#pragma unroll
        for (int k = 0; k < 32; ++k) ss += h[k] * h[k];
        float sc = 1.f / (sqrtf(ss) * 0.1767766952966369f + 1e-8f);
#pragma unroll
        for (int k = 0; k < 32; ++k) hs[tid][k] = fmaxf(h[k] * sc, 0.f);
    }
    __syncthreads();
    for (int cc = 0; cc < 6; ++cc) {
        int col = tid + cc * 256;
        float wcol[32];
#pragma unroll
        for (int k = 0; k < 32; ++k) wcol[k] = ow[k * D1C + col];
        float bb = ob[col];
        float* outp = a_r + ((size_t)col << 12) + s0;
        for (int r = 0; r < 64; ++r) {
            float acc = bb;
#pragma unroll
            for (int k = 0; k < 32; ++k) acc += hs[r][k] * wcol[k];
            outp[r] = acc;
        }
    }
}

// ---------------------------------------------------------------------------
// radix-4 4096-pt FFT in LDS (SoA re/im, +1-per-32 pad). DIF fwd produces
// digit-reversed order; DIT inv (exact mirror, conj twiddles) consumes it.
// Unnormalized: inverse returns 4096*x (caller pre-scales in pointwise step).
#define PHI(i) ((i) + ((i) >> 5))
#define FPAD 4224

__device__ __forceinline__ void fft_fwd(float* re, float* im, int tid, bool halfInput) {
    for (int m = 1024; m >= 1; m >>= 2) {
        __syncthreads();
        float c0 = -(float)M_PI * 0.5f / (float)m;
        for (int p = tid; p < 1024; p += 256) {
            int j  = p & (m - 1);
            int i0 = ((p - j) << 2) + j;
            int i1 = i0 + m, i2 = i1 + m, i3 = i2 + m;
            float x0r = re[PHI(i0)], x0i = im[PHI(i0)];
            float x1r = re[PHI(i1)], x1i = im[PHI(i1)];
            float x2r, x2i, x3r, x3i;
            if (halfInput && m == 1024) { x2r = 0.f; x2i = 0.f; x3r = 0.f; x3i = 0.f; }
            else { x2r = re[PHI(i2)]; x2i = im[PHI(i2)];
                   x3r = re[PHI(i3)]; x3i = im[PHI(i3)]; }
            float ar = x0r + x2r, ai = x0i + x2i;
            float br = x0r - x2r, bi = x0i - x2i;
            float cr = x1r + x3r, ci = x1i + x3i;
            float dr = x1r - x3r, di = x1i - x3i;
            re[PHI(i0)] = ar + cr; im[PHI(i0)] = ai + ci;
            float s1, c1; __sincosf(c0 * (float)j, &s1, &c1);
            float c2 = c1 * c1 - s1 * s1, s2 = 2.f * c1 * s1;
            float c3 = c2 * c1 - s2 * s1, s3 = s2 * c1 + c2 * s1;
            float t1r = br + di, t1i = bi - dr;                 // (b - i*d)
            re[PHI(i1)] = t1r * c1 - t1i * s1; im[PHI(i1)] = t1r * s1 + t1i * c1;
            float t2r = ar - cr, t2i = ai - ci;
            re[PHI(i2)] = t2r * c2 - t2i * s2; im[PHI(i2)] = t2r * s2 + t2i * c2;
            float t3r = br - di, t3i = bi + dr;                 // (b + i*d)
            re[PHI(i3)] = t3r * c3 - t3i * s3; im[PHI(i3)] = t3r * s3 + t3i * c3;
        }
    }
    __syncthreads();
}

__device__ __forceinline__ void fft_inv(float* re, float* im, int tid) {
    for (int m = 1; m <= 1024; m <<= 2) {
        __syncthreads();
        float c0 = (float)M_PI * 0.5f / (float)m;   // conj twiddles
        for (int p = tid; p < 1024; p += 256) {
            int j  = p & (m - 1);
            int i0 = ((p - j) << 2) + j;
            int i1 = i0 + m, i2 = i1 + m, i3 = i2 + m;
            float y0r = re[PHI(i0)], y0i = im[PHI(i0)];
            float y1r = re[PHI(i1)], y1i = im[PHI(i1)];
            float y2r = re[PHI(i2)], y2i = im[PHI(i2)];
            float y3r = re[PHI(i3)], y3i = im[PHI(i3)];
            float s1, c1; __sincosf(c0 * (float)j, &s1, &c1);
            float c2 = c1 * c1 - s1 * s1, s2 = 2.f * c1 * s1;
            float c3 = c2 * c1 - s2 * s1, s3 = s2 * c1 + c2 * s1;
            float p1r = y1r * c1 - y1i * s1, p1i = y1r * s1 + y1i * c1;
            float p2r = y2r * c2 - y2i * s2, p2i = y2r * s2 + y2i * c2;
            float p3r = y3r * c3 - y3i * s3, p3i = y3r * s3 + y3i * c3;
            float a2r = y0r + p2r, a2i = y0i + p2i;
            float g2r = y0r - p2r, g2i = y0i - p2i;
            float b2r = p1r + p3r, b2i = p1i + p3i;
            float er  = p3r - p1r, ei  = p3i - p1i;   // d2 = -i*(p3-p1)
            float d2r = ei, d2i = -er;
            re[PHI(i0)] = a2r + b2r; im[PHI(i0)] = a2i + b2i;
            re[PHI(i1)] = g2r + d2r; im[PHI(i1)] = g2i + d2i;
            re[PHI(i2)] = a2r - b2r; im[PHI(i2)] = a2i - b2i;
            re[PHI(i3)] = g2r - d2r; im[PHI(i3)] = g2i - d2i;
        }
    }
    __syncthreads();
}

// forward-FFT the (real) RPE coefficient rows -> af spectrum (digit-reversed)
__global__ __launch_bounds__(256) void fft_a_kernel(const float* __restrict__ a_r,
                                                    float2* __restrict__ af) {
    __shared__ float re[FPAD];
    __shared__ float im[FPAD];
    int tid = threadIdx.x;
    const float* row = a_r + ((size_t)blockIdx.x << 12);
    float2* orow     = af  + ((size_t)blockIdx.x << 12);
    for (int k = tid; k < NFFT; k += 256) { re[PHI(k)] = row[k]; im[PHI(k)] = 0.f; }
    fft_fwd(re, im, tid, false);
    for (int k = tid; k < NFFT; k += 256) orow[k] = make_float2(re[PHI(k)], im[PHI(k)]);
}

// packed circular convolution: z = v[b0] + i*v[b1] per column; one FFT pair
// serves two batch rows (ifft(Z*A) = t0 + i*t1, both real).
__global__ __launch_bounds__(256) void conv_kernel(float* __restrict__ vt,
                                                   const float2* __restrict__ af) {
    __shared__ float re[FPAD];
    __shared__ float im[FPAD];
    int tid = threadIdx.x;
    int pr  = blockIdx.x / D1C;          // batch pair: 0 -> (0,1), 1 -> (2,3)
    int col = blockIdx.x % D1C;
    float* v0 = vt + ((size_t)((2 * pr)     * D1C + col) << 11);
    float* v1 = vt + ((size_t)((2 * pr + 1) * D1C + col) << 11);
    const float2* arow = af + ((size_t)col << 12);
    for (int k = tid; k < 2048; k += 256) { re[PHI(k)] = v0[k]; im[PHI(k)] = v1[k]; }
    fft_fwd(re, im, tid, true);
    const float inv = 1.0f / 4096.0f;
    for (int k = tid; k < NFFT; k += 256) {
        int q = PHI(k);
        float zr = re[q], zi = im[q];
        float2 w = arow[k];
        re[q] = (zr * w.x - zi * w.y) * inv;
        im[q] = (zr * w.y + zi * w.x) * inv;
    }
    fft_inv(re, im, tid);
    for (int k = tid; k < 2048; k += 256) { v0[k] = re[PHI(k)]; v1[k] = im[PHI(k)]; }
}

// ---------------------------------------------------------------------------
// MFMA split-fp16 GEMM: C = Ah*Bh + Ah*Bl + Al*Bh, fp32 accum.
// A row-major [M][K] (hi/lo), B transposed [N][K] (hi/lo).
// 128x128 tile, BK=32, 4 waves (each 64x64), double-buffered global_load_lds.
enum { EP_SILU_F32, EP_SILU_VT, EP_PLAIN, EP_GLU2 };

template <int K, int EPI>
__global__ __launch_bounds__(256, 2) void mgemm(
    const f16* __restrict__ Ah, const f16* __restrict__ Al,
    const f16* __restrict__ Bh, const f16* __restrict__ Bl,
    const float* __restrict__ bias, const float* __restrict__ E0,
    float* __restrict__ OutF, f16* __restrict__ OutH, f16* __restrict__ OutL,
    int Ncols) {
    __shared__ __align__(16) char smem[65536];
    const int tid  = threadIdx.x;
    const int w    = tid >> 6, lane = tid & 63;
    const int wr   = w >> 1, wc = w & 1;
    const int l15  = lane & 15, kc = lane >> 4;
    const int row0 = blockIdx.x * 128, col0 = blockIdx.y * 128;

    f32x4 acc[4][4] = {};

    auto stage = [&](int buf, int kt) {
        const int k0 = kt * 32;
#pragma unroll
        for (int c = 0; c < 2; ++c) {
            int p = tid + c * 256;                 // 16B-position: kc*128 + row
            int r = p & 127, kk = p >> 7;
            const f16* ga = Ah + (size_t)(row0 + r) * K + k0 + kk * 8;
            const f16* gb = Al + (size_t)(row0 + r) * K + k0 + kk * 8;
            const f16* gc = Bh + (size_t)(col0 + r) * K + k0 + kk * 8;
            const f16* gd = Bl + (size_t)(col0 + r) * K + k0 + kk * 8;
            u32 off = (u32)buf * 32768u + (u32)(c * 256 + w * 64) * 16u;  // wave-uniform
            __builtin_amdgcn_global_load_lds((const __attribute__((address_space(1))) u32*)ga,
                (__attribute__((address_space(3))) u32*)(smem + off), 16, 0, 0);
            __builtin_amdgcn_global_load_lds((const __attribute__((address_space(1))) u32*)gb,
                (__attribute__((address_space(3))) u32*)(smem + off + 8192), 16, 0, 0);
            __builtin_amdgcn_global_load_lds((const __attribute__((address_space(1))) u32*)gc,
                (__attribute__((address_space(3))) u32*)(smem + off + 16384), 16, 0, 0);
            __builtin_amdgcn_global_load_lds((const __attribute__((address_space(1))) u32*)gd,
                (__attribute__((address_space(3))) u32*)(smem + off + 24576), 16, 0, 0);
        }
    };

    auto compute = [&](int buf) {
        const char* base = smem + buf * 32768;
        f16x8 a_h[4], a_l[4], b_h[4], b_l[4];
#pragma unroll
        for (int m = 0; m < 4; ++m) {
            int r = wr * 64 + m * 16 + l15;
            a_h[m] = *(const f16x8*)(base + (kc * 128 + r) * 16);
            a_l[m] = *(const f16x8*)(base + 8192 + (kc * 128 + r) * 16);
        }
#pragma unroll
        for (int n = 0; n < 4; ++n) {
            int r = wc * 64 + n * 16 + l15;
            b_h[n] = *(const f16x8*)(base + 16384 + (kc * 128 + r) * 16);
            b_l[n] = *(const f16x8*)(base + 24576 + (kc * 128 + r) * 16);
        }
#pragma unroll
        for (int m = 0; m < 4; ++m)
#pragma unroll
            for (int n = 0; n < 4; ++n) {
                acc[m][n] = __builtin_amdgcn_mfma_f32_16x16x32_f16(a_h[m], b_h[n], acc[m][n], 0, 0, 0);
                acc[m][n] = __builtin_amdgcn_mfma_f32_16x16x32_f16(a_h[m], b_l[n], acc[m][n], 0, 0, 0);
                acc[m][n] = __builtin_amdgcn_mfma_f32_16x16x32_f16(a_l[m], b_h[n], acc[m][n], 0, 0, 0);
            }
    };

    constexpr int NT = K / 32;
    stage(0, 0);
    __syncthreads();
    int cur = 0;
    for (int t = 0; t < NT; ++t) {
        if (t + 1 < NT) stage(cur ^ 1, t + 1);
        compute(cur);
        __syncthreads();
        cur ^= 1;
    }

#pragma unroll
    for (int m = 0; m < 4; ++m) {
        int rbase = row0 + wr * 64 + m * 16 + kc * 4;
#pragma unroll
        for (int n = 0; n < 4; ++n) {
            int col = col0 + wc * 64 + n * 16 + l15;
            float bb = bias[col];
#pragma unroll
            for (int r = 0; r < 4; ++r) {
                int row = rbase + r;
                float y = acc[m][n][r] + bb;
                size_t idx = (size_t)row * Ncols + col;
                if constexpr (EPI == EP_SILU_F32) {
                    OutF[idx] = silu_f(y);
                } else if constexpr (EPI == EP_SILU_VT) {
                    int bI = row >> 11, ni = row & 2047;
                    OutF[(((size_t)(bI * D1C + col)) << 11) + ni] = silu_f(y);
                } else if constexpr (EPI == EP_PLAIN) {
                    OutF[idx] = y;
                } else {  // EP_GLU2: z = E0 * y -> f16 hi/lo
                    float z = E0[idx] * y;
                    f16 h = (f16)z;
                    OutH[idx] = h;
                    OutL[idx] = (f16)(z - (float)h);
                }
            }
        }
    }
}

// ---------------------------------------------------------------------------
extern "C" void kernel_launch(void* const* d_in, const int* in_sizes, int n_in,
                              void* d_out, int out_size, void* d_ws, size_t ws_size,
                              hipStream_t stream) {
    const float* x   = (const float*)d_in[1];
    const float* u_w = (const float*)d_in[2];
    const float* u_b = (const float*)d_in[3];
    const float* v_w = (const float*)d_in[4];
    const float* v_b = (const float*)d_in[5];
    const float* o_w = (const float*)d_in[6];
    const float* o_b = (const float*)d_in[7];
    const float* rpw = (const float*)d_in[8];
    const float* rpb = (const float*)d_in[9];
    const float* rlw = (const float*)d_in[10];
    const float* rlb = (const float*)d_in[11];
    const float* row_w = (const float*)d_in[12];
    const float* rob = (const float*)d_in[13];
    const float* g1w = (const float*)d_in[14];
    const float* g1b = (const float*)d_in[15];
    const float* g2w = (const float*)d_in[16];
    const float* g2b = (const float*)d_in[17];
    const float* g3w = (const float*)d_in[18];
    const float* g3b = (const float*)d_in[19];

    // workspace layout (bytes)
    char* wsb = (char*)d_ws;
    float* scale = (float*)wsb;                       // 64 KB slot
    char* R1 = wsb + (1 << 16);                       // 50331648: af spectrum, later ph+pl
    char* R2 = R1 + 50331648;                         // 50331648: vt, later tmp1
    char* R3 = R2 + 50331648;                         // 50331648: a_r, then u, later zh+zl
    char* R4 = R3 + 50331648;                         // 16777216: xn hi/lo, later x2 hi/lo
    char* R5 = R4 + 16777216;                         // 18874368: 6 transposed split weights

    float2* af   = (float2*)R1;
    f16*    ph   = (f16*)R1;
    f16*    pl   = (f16*)(R1 + 25165824);
    float*  vt   = (float*)R2;
    float*  tmp1 = (float*)R2;
    float*  a_r  = (float*)R3;   // dead before u is written
    float*  u    = (float*)R3;
    f16*    zh   = (f16*)R3;
    f16*    zl   = (f16*)(R3 + 25165824);
    f16*    xnh  = (f16*)R4;
    f16*    xnl  = (f16*)(R4 + 8388608);
    f16*    x2h  = xnh;  // reuse after xn dead
    f16*    x2l  = xnl;

    auto wTh = [&](int i) { return (f16*)(R5 + (size_t)i * 3145728); };
    auto wTl = [&](int i) { return (f16*)(R5 + (size_t)i * 3145728 + 1572864); };

    float* g_out   = (float*)d_out;
    float* out_out = g_out + (size_t)BATCH * NSEQ * EMBC;

    // prologue: norms, splits, weight transposes, RPE spectrum
    scale_kernel<<<2048, 256, 0, stream>>>(x, scale);
    convert_xn_kernel<<<4096, 256, 0, stream>>>(x, scale, xnh, xnl);
    wtrans_kernel<<<dim3(48, 16), 256, 0, stream>>>(u_w, wTh(0), wTl(0), 512, 1536);
    wtrans_kernel<<<dim3(48, 16), 256, 0, stream>>>(v_w, wTh(1), wTl(1), 512, 1536);
    wtrans_kernel<<<dim3(16, 48), 256, 0, stream>>>(o_w, wTh(2), wTl(2), 1536, 512);
    wtrans_kernel<<<dim3(48, 16), 256, 0, stream>>>(g1w, wTh(3), wTl(3), 512, 1536);
    wtrans_kernel<<<dim3(48, 16), 256, 0, stream>>>(g2w, wTh(4), wTl(4), 512, 1536);
    wtrans_kernel<<<dim3(16, 48), 256, 0, stream>>>(g3w, wTh(5), wTl(5), 1536, 512);
    rpe_kernel<<<64, 256, 0, stream>>>(rpw, rpb, rlw, rlb, row_w, rob, a_r);
    fft_a_kernel<<<1536, 256, 0, stream>>>(a_r, af);

    // u, v projections
    mgemm<512, EP_SILU_F32><<<dim3(64, 12), 256, 0, stream>>>(
        xnh, xnl, wTh(0), wTl(0), u_b, nullptr, u, nullptr, nullptr, 1536);
    mgemm<512, EP_SILU_VT><<<dim3(64, 12), 256, 0, stream>>>(
        xnh, xnl, wTh(1), wTl(1), v_b, nullptr, vt, nullptr, nullptr, 1536);

    // Toeplitz via packed FFT conv (in place on vt), then p = u * t -> f16 split
    conv_kernel<<<3072, 256, 0, stream>>>(vt, af);
    convert_p_kernel<<<dim3(64, 48, 4), 256, 0, stream>>>(u, vt, ph, pl);

    // out = p @ o_w + o_b
    mgemm<1536, EP_PLAIN><<<dim3(64, 4), 256, 0, stream>>>(
        ph, pl, wTh(2), wTl(2), o_b, nullptr, out_out, nullptr, nullptr, 512);

    // GLU
    convert_x2_kernel<<<4096, 256, 0, stream>>>(out_out, x, x2h, x2l);
    mgemm<512, EP_SILU_F32><<<dim3(64, 12), 256, 0, stream>>>(
        x2h, x2l, wTh(3), wTl(3), g1b, nullptr, tmp1, nullptr, nullptr, 1536);
    mgemm<512, EP_GLU2><<<dim3(64, 12), 256, 0, stream>>>(
        x2h, x2l, wTh(4), wTl(4), g2b, tmp1, nullptr, zh, zl, 1536);
    mgemm<1536, EP_PLAIN><<<dim3(64, 4), 256, 0, stream>>>(
        zh, zl, wTh(5), wTl(5), g3b, nullptr, g_out, nullptr, nullptr, 512);
}

// Round 4
// 672.939 us; speedup vs baseline: 2.5761x; 1.1789x over previous
//
#include <hip/hip_runtime.h>
#include <math.h>

#define NSEQ 2048
#define NFFT 4096
#define D1C  1536
#define EMBC 512
#define BATCH 4

typedef __fp16 f16;
typedef __fp16 f16x8 __attribute__((ext_vector_type(8)));
typedef __fp16 f16x4 __attribute__((ext_vector_type(4)));
typedef float  f32x4 __attribute__((ext_vector_type(4)));
typedef unsigned int u32;

__device__ __forceinline__ float silu_f(float y) { return y / (1.f + expf(-y)); }

// ---------------------------------------------------------------------------
// row-norm scale: scale[row] = 1/(||x_row|| * D1^-0.5 + 1e-8)
__global__ __launch_bounds__(256) void scale_kernel(const float* __restrict__ x,
                                                    float* __restrict__ scale) {
    int row  = blockIdx.x * 4 + (threadIdx.x >> 6);
    int lane = threadIdx.x & 63;
    const float* xr = x + (size_t)row * EMBC;
    float ss = 0.f;
#pragma unroll
    for (int k = 0; k < EMBC / 64; ++k) { float v = xr[lane + k * 64]; ss += v * v; }
#pragma unroll
    for (int off = 32; off >= 1; off >>= 1) ss += __shfl_xor(ss, off);
    if (lane == 0) scale[row] = 1.f / (sqrtf(ss) * 0.02551551815399144f + 1e-8f);
}

// xn = x * scale  -> f16 hi/lo
__global__ __launch_bounds__(256) void convert_xn_kernel(
    const float* __restrict__ x, const float* __restrict__ scale,
    f16* __restrict__ xh, f16* __restrict__ xl) {
    size_t i = ((size_t)blockIdx.x * 256 + threadIdx.x) * 4;
    float4 v = *reinterpret_cast<const float4*>(x + i);
    float s = scale[i >> 9];
    f16x4 h, l;
    const float* vv = (const float*)&v;
#pragma unroll
    for (int j = 0; j < 4; ++j) {
        float val = vv[j] * s;
        f16 hh = (f16)val;
        h[j] = hh; l[j] = (f16)(val - (float)hh);
    }
    *reinterpret_cast<f16x4*>(xh + i) = h;
    *reinterpret_cast<f16x4*>(xl + i) = l;
}

// x2 = a + b -> f16 hi/lo
__global__ __launch_bounds__(256) void convert_x2_kernel(
    const float* __restrict__ a, const float* __restrict__ b,
    f16* __restrict__ xh, f16* __restrict__ xl) {
    size_t i = ((size_t)blockIdx.x * 256 + threadIdx.x) * 4;
    float4 va = *reinterpret_cast<const float4*>(a + i);
    float4 vb = *reinterpret_cast<const float4*>(b + i);
    const float* pa = (const float*)&va;
    const float* pb = (const float*)&vb;
    f16x4 h, l;
#pragma unroll
    for (int j = 0; j < 4; ++j) {
        float val = pa[j] + pb[j];
        f16 hh = (f16)val;
        h[j] = hh; l[j] = (f16)(val - (float)hh);
    }
    *reinterpret_cast<f16x4*>(xh + i) = h;
    *reinterpret_cast<f16x4*>(xl + i) = l;
}

// W[K][N] fp32 -> WT[N][K] f16 hi only (LDS tile transpose)
__global__ __launch_bounds__(256) void wtrans_kernel(const float* __restrict__ W,
        f16* __restrict__ Th, int Kd, int Nd) {
    __shared__ float t[32][33];
    int tx = threadIdx.x & 31, ty = threadIdx.x >> 5;
    int n0 = blockIdx.x * 32, k0 = blockIdx.y * 32;
#pragma unroll
    for (int yy = ty; yy < 32; yy += 8)
        t[yy][tx] = W[(size_t)(k0 + yy) * Nd + n0 + tx];
    __syncthreads();
#pragma unroll
    for (int yy = ty; yy < 32; yy += 8) {
        float v = t[tx][yy];
        Th[(size_t)(n0 + yy) * Kd + k0 + tx] = (f16)v;
    }
}

// p = u * t (vt layout [b][col][n]) -> f16 hi/lo row-major [8192][1536]
__global__ __launch_bounds__(256) void convert_p_kernel(
    const float* __restrict__ u, const float* __restrict__ vt,
    f16* __restrict__ ph, f16* __restrict__ pl) {
    __shared__ float t[32][33];
    int b = blockIdx.z, n0 = blockIdx.x * 32, c0 = blockIdx.y * 32;
    int tx = threadIdx.x & 31, ty = threadIdx.x >> 5;
#pragma unroll
    for (int yy = ty; yy < 32; yy += 8)
        t[yy][tx] = vt[(((size_t)(b * D1C + c0 + yy)) << 11) + n0 + tx];
    __syncthreads();
#pragma unroll
    for (int yy = ty; yy < 32; yy += 8) {
        int row = b * NSEQ + n0 + yy;
        size_t idx = (size_t)row * D1C + c0 + tx;
        float val = u[idx] * t[tx][yy];
        f16 h = (f16)val;
        ph[idx] = h; pl[idx] = (f16)(val - (float)h);
    }
}

// ---------------------------------------------------------------------------
// RPE MLP: 4096 positions -> a_r[col][pos] (real), col = h*HD+d
__global__ __launch_bounds__(256) void rpe_kernel(
    const float* __restrict__ pw, const float* __restrict__ pb,
    const float* __restrict__ lw, const float* __restrict__ lb,
    const float* __restrict__ ow, const float* __restrict__ ob,
    float* __restrict__ a_r) {
    __shared__ float hs[64][33];
    int tid = threadIdx.x;
    int s0  = blockIdx.x * 64;
    if (tid < 64) {
        int s = s0 + tid;
        float p = (s == 0 || s == 2048) ? 0.f : (s < 2048 ? (float)s : (float)(s - 4096));
        float h[32];
#pragma unroll
        for (int k = 0; k < 32; ++k) h[k] = fmaxf(p * pw[k] + pb[k], 0.f);
        for (int L = 0; L < 3; ++L) {
            float ss = 0.f;
#pragma unroll
            for (int k = 0; k < 32; ++k) ss += h[k] * h[k];
            float sc = 1.f / (sqrtf(ss) * 0.1767766952966369f + 1e-8f);
            float g[32];
#pragma unroll
            for (int k = 0; k < 32; ++k) g[k] = fmaxf(h[k] * sc, 0.f);
#pragma unroll
            for (int j = 0; j < 32; ++j) {
                float acc = lb[L * 32 + j];
#pragma unroll
                for (int k = 0; k < 32; ++k) acc += g[k] * lw[(L * 32 + k) * 32 + j];
                h[j] = acc;
            }
        }
        float ss = 0.f;
#pragma unroll
        for (int k = 0; k < 32; ++k) ss += h[k] * h[k];
        float sc = 1.f / (sqrtf(ss) * 0.1767766952966369f + 1e-8f);
#pragma unroll
        for (int k = 0; k < 32; ++k) hs[tid][k] = fmaxf(h[k] * sc, 0.f);
    }
    __syncthreads();
    for (int cc = 0; cc < 6; ++cc) {
        int col = tid + cc * 256;
        float wcol[32];
#pragma unroll
        for (int k = 0; k < 32; ++k) wcol[k] = ow[k * D1C + col];
        float bb = ob[col];
        float* outp = a_r + ((size_t)col << 12) + s0;
        for (int r = 0; r < 64; ++r) {
            float acc = bb;
#pragma unroll
            for (int k = 0; k < 32; ++k) acc += hs[r][k] * wcol[k];
            outp[r] = acc;
        }
    }
}

// ---------------------------------------------------------------------------
// radix-4 4096-pt FFT in LDS (SoA re/im, +1-per-32 pad).
#define PHI(i) ((i) + ((i) >> 5))
#define FPAD 4224

__device__ __forceinline__ void fft_fwd(float* re, float* im, int tid, bool halfInput) {
    for (int m = 1024; m >= 1; m >>= 2) {
        __syncthreads();
        float c0 = -(float)M_PI * 0.5f / (float)m;
        for (int p = tid; p < 1024; p += 256) {
            int j  = p & (m - 1);
            int i0 = ((p - j) << 2) + j;
            int i1 = i0 + m, i2 = i1 + m, i3 = i2 + m;
            float x0r = re[PHI(i0)], x0i = im[PHI(i0)];
            float x1r = re[PHI(i1)], x1i = im[PHI(i1)];
            float x2r, x2i, x3r, x3i;
            if (halfInput && m == 1024) { x2r = 0.f; x2i = 0.f; x3r = 0.f; x3i = 0.f; }
            else { x2r = re[PHI(i2)]; x2i = im[PHI(i2)];
                   x3r = re[PHI(i3)]; x3i = im[PHI(i3)]; }
            float ar = x0r + x2r, ai = x0i + x2i;
            float br = x0r - x2r, bi = x0i - x2i;
            float cr = x1r + x3r, ci = x1i + x3i;
            float dr = x1r - x3r, di = x1i - x3i;
            re[PHI(i0)] = ar + cr; im[PHI(i0)] = ai + ci;
            float s1, c1; __sincosf(c0 * (float)j, &s1, &c1);
            float c2 = c1 * c1 - s1 * s1, s2 = 2.f * c1 * s1;
            float c3 = c2 * c1 - s2 * s1, s3 = s2 * c1 + c2 * s1;
            float t1r = br + di, t1i = bi - dr;
            re[PHI(i1)] = t1r * c1 - t1i * s1; im[PHI(i1)] = t1r * s1 + t1i * c1;
            float t2r = ar - cr, t2i = ai - ci;
            re[PHI(i2)] = t2r * c2 - t2i * s2; im[PHI(i2)] = t2r * s2 + t2i * c2;
            float t3r = br - di, t3i = bi + dr;
            re[PHI(i3)] = t3r * c3 - t3i * s3; im[PHI(i3)] = t3r * s3 + t3i * c3;
        }
    }
    __syncthreads();
}

__device__ __forceinline__ void fft_inv(float* re, float* im, int tid) {
    for (int m = 1; m <= 1024; m <<= 2) {
        __syncthreads();
        float c0 = (float)M_PI * 0.5f / (float)m;
        for (int p = tid; p < 1024; p += 256) {
            int j  = p & (m - 1);
            int i0 = ((p - j) << 2) + j;
            int i1 = i0 + m, i2 = i1 + m, i3 = i2 + m;
            float y0r = re[PHI(i0)], y0i = im[PHI(i0)];
            float y1r = re[PHI(i1)], y1i = im[PHI(i1)];
            float y2r = re[PHI(i2)], y2i = im[PHI(i2)];
            float y3r = re[PHI(i3)], y3i = im[PHI(i3)];
            float s1, c1; __sincosf(c0 * (float)j, &s1, &c1);
            float c2 = c1 * c1 - s1 * s1, s2 = 2.f * c1 * s1;
            float c3 = c2 * c1 - s2 * s1, s3 = s2 * c1 + c2 * s1;
            float p1r = y1r * c1 - y1i * s1, p1i = y1r * s1 + y1i * c1;
            float p2r = y2r * c2 - y2i * s2, p2i = y2r * s2 + y2i * c2;
            float p3r = y3r * c3 - y3i * s3, p3i = y3r * s3 + y3i * c3;
            float a2r = y0r + p2r, a2i = y0i + p2i;
            float g2r = y0r - p2r, g2i = y0i - p2i;
            float b2r = p1r + p3r, b2i = p1i + p3i;
            float er  = p3r - p1r, ei  = p3i - p1i;
            float d2r = ei, d2i = -er;
            re[PHI(i0)] = a2r + b2r; im[PHI(i0)] = a2i + b2i;
            re[PHI(i1)] = g2r + d2r; im[PHI(i1)] = g2i + d2i;
            re[PHI(i2)] = a2r - b2r; im[PHI(i2)] = a2i - b2i;
            re[PHI(i3)] = g2r - d2r; im[PHI(i3)] = g2i - d2i;
        }
    }
    __syncthreads();
}

__global__ __launch_bounds__(256) void fft_a_kernel(const float* __restrict__ a_r,
                                                    float2* __restrict__ af) {
    __shared__ float re[FPAD];
    __shared__ float im[FPAD];
    int tid = threadIdx.x;
    const float* row = a_r + ((size_t)blockIdx.x << 12);
    float2* orow     = af  + ((size_t)blockIdx.x << 12);
    for (int k = tid; k < NFFT; k += 256) { re[PHI(k)] = row[k]; im[PHI(k)] = 0.f; }
    fft_fwd(re, im, tid, false);
    for (int k = tid; k < NFFT; k += 256) orow[k] = make_float2(re[PHI(k)], im[PHI(k)]);
}

__global__ __launch_bounds__(256) void conv_kernel(float* __restrict__ vt,
                                                   const float2* __restrict__ af) {
    __shared__ float re[FPAD];
    __shared__ float im[FPAD];
    int tid = threadIdx.x;
    int pr  = blockIdx.x / D1C;
    int col = blockIdx.x % D1C;
    float* v0 = vt + ((size_t)((2 * pr)     * D1C + col) << 11);
    float* v1 = vt + ((size_t)((2 * pr + 1) * D1C + col) << 11);
    const float2* arow = af + ((size_t)col << 12);
    for (int k = tid; k < 2048; k += 256) { re[PHI(k)] = v0[k]; im[PHI(k)] = v1[k]; }
    fft_fwd(re, im, tid, true);
    const float inv = 1.0f / 4096.0f;
    for (int k = tid; k < NFFT; k += 256) {
        int q = PHI(k);
        float zr = re[q], zi = im[q];
        float2 w = arow[k];
        re[q] = (zr * w.x - zi * w.y) * inv;
        im[q] = (zr * w.y + zi * w.x) * inv;
    }
    fft_inv(re, im, tid);
    for (int k = tid; k < 2048; k += 256) { v0[k] = re[PHI(k)]; v1[k] = im[PHI(k)]; }
}

// ---------------------------------------------------------------------------
// MFMA 2-pass split-f16 GEMM: C = (Ah+Al)*Bh, fp32 accum (B rounded to f16).
// A row-major [M][K] hi/lo, B transposed [N][K] hi. BN=128, 4 waves (2x2),
// double-buffered global_load_lds, bijective XCD swizzle, float4 epilogue.
enum { EP_SILU_F32, EP_SILU_VT, EP_PLAIN, EP_GLU2 };

template <int BM, int K, int EPI>
__global__ __launch_bounds__(256, (BM == 128 ? 3 : 4)) void mgemm(
    const f16* __restrict__ Ah, const f16* __restrict__ Al,
    const f16* __restrict__ Bh,
    const float* __restrict__ bias, const float* __restrict__ E0,
    float* __restrict__ OutF, f16* __restrict__ OutH, f16* __restrict__ OutL,
    int Ncols) {
    constexpr int SB   = BM * 128 + 8192;        // bytes per K-tile buffer
    constexpr int MREP = BM / 32;                // frags per wave in M
    constexpr int LOGB = (BM == 128 ? 7 : 6);
    constexpr int CA   = BM / 64;                // A chunks per thread per stream
    __shared__ __align__(16) char smem[2 * SB];

    const int tid  = threadIdx.x;
    const int w    = tid >> 6, lane = tid & 63;
    const int wr   = w >> 1, wc = w & 1;
    const int l15  = lane & 15, kc = lane >> 4;

    // bijective XCD swizzle (m204), bx-major chunks
    const int NBY = Ncols >> 7;
    const int nwg = gridDim.x;
    int flat = blockIdx.x;
    int q8 = nwg >> 3, r8 = nwg & 7;
    int xcd = flat & 7, pos = flat >> 3;
    int wg = (xcd < r8 ? xcd * (q8 + 1) : r8 * (q8 + 1) + (xcd - r8) * q8) + pos;
    const int row0 = (wg / NBY) * BM;
    const int col0 = (wg % NBY) * 128;

    f32x4 acc[MREP][4] = {};

    auto stage = [&](int buf, int kt) {
        const int k0 = kt * 32;
        const int bb = buf * SB;
#pragma unroll
        for (int l = 0; l < CA; ++l) {
            int ci = tid + l * 256;
            int r = ci & (BM - 1), kk = ci >> LOGB;
            const f16* ga = Ah + (size_t)(row0 + r) * K + k0 + kk * 8;
            const f16* gb = Al + (size_t)(row0 + r) * K + k0 + kk * 8;
            __builtin_amdgcn_global_load_lds((const __attribute__((address_space(1))) u32*)ga,
                (__attribute__((address_space(3))) u32*)(smem + bb + ci * 16), 16, 0, 0);
            __builtin_amdgcn_global_load_lds((const __attribute__((address_space(1))) u32*)gb,
                (__attribute__((address_space(3))) u32*)(smem + bb + BM * 64 + ci * 16), 16, 0, 0);
        }
#pragma unroll
        for (int l = 0; l < 2; ++l) {
            int ci = tid + l * 256;
            int c = ci & 127, kk = ci >> 7;
            const f16* gc = Bh + (size_t)(col0 + c) * K + k0 + kk * 8;
            __builtin_amdgcn_global_load_lds((const __attribute__((address_space(1))) u32*)gc,
                (__attribute__((address_space(3))) u32*)(smem + bb + BM * 128 + ci * 16), 16, 0, 0);
        }
    };

    auto compute = [&](int buf) {
        const char* base = smem + buf * SB;
        f16x8 a_h[MREP], a_l[MREP], b_h[4];
#pragma unroll
        for (int m = 0; m < MREP; ++m) {
            int r = wr * (BM / 2) + m * 16 + l15;
            a_h[m] = *(const f16x8*)(base + (kc * BM + r) * 16);
            a_l[m] = *(const f16x8*)(base + BM * 64 + (kc * BM + r) * 16);
        }
#pragma unroll
        for (int n = 0; n < 4; ++n) {
            int c = wc * 64 + n * 16 + l15;
            b_h[n] = *(const f16x8*)(base + BM * 128 + (kc * 128 + c) * 16);
        }
#pragma unroll
        for (int m = 0; m < MREP; ++m)
#pragma unroll
            for (int n = 0; n < 4; ++n) {
                acc[m][n] = __builtin_amdgcn_mfma_f32_16x16x32_f16(a_h[m], b_h[n], acc[m][n], 0, 0, 0);
                acc[m][n] = __builtin_amdgcn_mfma_f32_16x16x32_f16(a_l[m], b_h[n], acc[m][n], 0, 0, 0);
            }
    };

    constexpr int NT = K / 32;
    stage(0, 0);
    __syncthreads();
    int cur = 0;
    for (int t = 0; t < NT; ++t) {
        if (t + 1 < NT) stage(cur ^ 1, t + 1);
        compute(cur);
        __syncthreads();
        cur ^= 1;
    }

    // -------- vectorized epilogue via LDS repack (float4 stores) --------
    const int WRB = wr * (BM / 2);
    if constexpr (EPI == EP_SILU_VT) {
        float* patch = (float*)(smem + w * 5376);        // [64][20] f32, padded
#pragma unroll
        for (int m = 0; m < MREP; ++m) {
            __syncthreads();
#pragma unroll
            for (int n = 0; n < 4; ++n)
#pragma unroll
                for (int r = 0; r < 4; ++r)
                    patch[(n * 16 + l15) * 20 + kc * 4 + r] = acc[m][n][r];
            __syncthreads();
#pragma unroll
            for (int t = 0; t < 4; ++t) {
                int qi = lane + t * 64;
                int col_ = qi >> 2, rq = qi & 3;
                float4 y = *(const float4*)&patch[col_ * 20 + rq * 4];
                int col = col0 + wc * 64 + col_;
                float bb = bias[col];
                y.x = silu_f(y.x + bb); y.y = silu_f(y.y + bb);
                y.z = silu_f(y.z + bb); y.w = silu_f(y.w + bb);
                int b = row0 >> 11;
                int seq = (row0 & 2047) + WRB + m * 16 + rq * 4;
                *(float4*)&OutF[(((size_t)(b * D1C + col)) << 11) + seq] = y;
            }
        }
    } else {
        float* patch = (float*)(smem + w * 4352);        // [16][68] f32, padded
#pragma unroll
        for (int m = 0; m < MREP; ++m) {
            __syncthreads();
#pragma unroll
            for (int n = 0; n < 4; ++n)
#pragma unroll
                for (int r = 0; r < 4; ++r)
                    patch[(kc * 4 + r) * 68 + n * 16 + l15] = acc[m][n][r];
            __syncthreads();
#pragma unroll
            for (int t = 0; t < 4; ++t) {
                int qi = lane + t * 64;
                int row_ = qi >> 4, q = qi & 15;
                float4 y = *(const float4*)&patch[row_ * 68 + q * 4];
                int row = row0 + WRB + m * 16 + row_;
                int col = col0 + wc * 64 + q * 4;
                float4 bb = *(const float4*)&bias[col];
                y.x += bb.x; y.y += bb.y; y.z += bb.z; y.w += bb.w;
                size_t idx = (size_t)row * Ncols + col;
                if constexpr (EPI == EP_SILU_F32) {
                    y.x = silu_f(y.x); y.y = silu_f(y.y);
                    y.z = silu_f(y.z); y.w = silu_f(y.w);
                    *(float4*)&OutF[idx] = y;
                } else if constexpr (EPI == EP_PLAIN) {
                    *(float4*)&OutF[idx] = y;
                } else {  // EP_GLU2
                    float4 e = *(const float4*)&E0[idx];
                    float z0 = e.x * y.x, z1 = e.y * y.y, z2 = e.z * y.z, z3 = e.w * y.w;
                    f16x4 h, l;
                    h[0] = (f16)z0; l[0] = (f16)(z0 - (float)h[0]);
                    h[1] = (f16)z1; l[1] = (f16)(z1 - (float)h[1]);
                    h[2] = (f16)z2; l[2] = (f16)(z2 - (float)h[2]);
                    h[3] = (f16)z3; l[3] = (f16)(z3 - (float)h[3]);
                    *(f16x4*)&OutH[idx] = h;
                    *(f16x4*)&OutL[idx] = l;
                }
            }
        }
    }
}

// ---------------------------------------------------------------------------
extern "C" void kernel_launch(void* const* d_in, const int* in_sizes, int n_in,
                              void* d_out, int out_size, void* d_ws, size_t ws_size,
                              hipStream_t stream) {
    const float* x   = (const float*)d_in[1];
    const float* u_w = (const float*)d_in[2];
    const float* u_b = (const float*)d_in[3];
    const float* v_w = (const float*)d_in[4];
    const float* v_b = (const float*)d_in[5];
    const float* o_w = (const float*)d_in[6];
    const float* o_b = (const float*)d_in[7];
    const float* rpw = (const float*)d_in[8];
    const float* rpb = (const float*)d_in[9];
    const float* rlw = (const float*)d_in[10];
    const float* rlb = (const float*)d_in[11];
    const float* row_w = (const float*)d_in[12];
    const float* rob = (const float*)d_in[13];
    const float* g1w = (const float*)d_in[14];
    const float* g1b = (const float*)d_in[15];
    const float* g2w = (const float*)d_in[16];
    const float* g2b = (const float*)d_in[17];
    const float* g3w = (const float*)d_in[18];
    const float* g3b = (const float*)d_in[19];

    // workspace layout (bytes)
    char* wsb = (char*)d_ws;
    float* scale = (float*)wsb;                       // 64 KB slot
    char* R1 = wsb + (1 << 16);                       // 50331648: af spectrum, later ph+pl
    char* R2 = R1 + 50331648;                         // 50331648: vt, later tmp1
    char* R3 = R2 + 50331648;                         // 50331648: a_r, then u, later zh+zl
    char* R4 = R3 + 50331648;                         // 16777216: xn hi/lo, later x2 hi/lo
    char* R5 = R4 + 16777216;                         // 9437184: 6 transposed f16 weights

    float2* af   = (float2*)R1;
    f16*    ph   = (f16*)R1;
    f16*    pl   = (f16*)(R1 + 25165824);
    float*  vt   = (float*)R2;
    float*  tmp1 = (float*)R2;
    float*  a_r  = (float*)R3;
    float*  u    = (float*)R3;
    f16*    zh   = (f16*)R3;
    f16*    zl   = (f16*)(R3 + 25165824);
    f16*    xnh  = (f16*)R4;
    f16*    xnl  = (f16*)(R4 + 8388608);
    f16*    x2h  = xnh;
    f16*    x2l  = xnl;

    auto wTh = [&](int i) { return (f16*)(R5 + (size_t)i * 1572864); };

    float* g_out   = (float*)d_out;
    float* out_out = g_out + (size_t)BATCH * NSEQ * EMBC;

    // prologue
    scale_kernel<<<2048, 256, 0, stream>>>(x, scale);
    convert_xn_kernel<<<4096, 256, 0, stream>>>(x, scale, xnh, xnl);
    wtrans_kernel<<<dim3(48, 16), 256, 0, stream>>>(u_w, wTh(0), 512, 1536);
    wtrans_kernel<<<dim3(48, 16), 256, 0, stream>>>(v_w, wTh(1), 512, 1536);
    wtrans_kernel<<<dim3(16, 48), 256, 0, stream>>>(o_w, wTh(2), 1536, 512);
    wtrans_kernel<<<dim3(48, 16), 256, 0, stream>>>(g1w, wTh(3), 512, 1536);
    wtrans_kernel<<<dim3(48, 16), 256, 0, stream>>>(g2w, wTh(4), 512, 1536);
    wtrans_kernel<<<dim3(16, 48), 256, 0, stream>>>(g3w, wTh(5), 1536, 512);
    rpe_kernel<<<64, 256, 0, stream>>>(rpw, rpb, rlw, rlb, row_w, rob, a_r);
    fft_a_kernel<<<1536, 256, 0, stream>>>(a_r, af);

    // u, v projections (M=8192, N=1536, K=512)
    mgemm<128, 512, EP_SILU_F32><<<768, 256, 0, stream>>>(
        xnh, xnl, wTh(0), u_b, nullptr, u, nullptr, nullptr, 1536);
    mgemm<128, 512, EP_SILU_VT><<<768, 256, 0, stream>>>(
        xnh, xnl, wTh(1), v_b, nullptr, vt, nullptr, nullptr, 1536);

    // Toeplitz via packed FFT conv, then p = u * t -> f16 split
    conv_kernel<<<3072, 256, 0, stream>>>(vt, af);
    convert_p_kernel<<<dim3(64, 48, 4), 256, 0, stream>>>(u, vt, ph, pl);

    // out = p @ o_w + o_b  (N=512, K=1536)
    mgemm<64, 1536, EP_PLAIN><<<512, 256, 0, stream>>>(
        ph, pl, wTh(2), o_b, nullptr, out_out, nullptr, nullptr, 512);

    // GLU
    convert_x2_kernel<<<4096, 256, 0, stream>>>(out_out, x, x2h, x2l);
    mgemm<128, 512, EP_SILU_F32><<<768, 256, 0, stream>>>(
        x2h, x2l, wTh(3), g1b, nullptr, tmp1, nullptr, nullptr, 1536);
    mgemm<128, 512, EP_GLU2><<<768, 256, 0, stream>>>(
        x2h, x2l, wTh(4), g2b, tmp1, nullptr, zh, zl, 1536);
    mgemm<64, 1536, EP_PLAIN><<<512, 256, 0, stream>>>(
        zh, zl, wTh(5), g3b, nullptr, g_out, nullptr, nullptr, 512);
}